// Round 8
// baseline (990.002 us; speedup 1.0000x reference)
//
#include <hip/hip_runtime.h>
#include <hip/hip_cooperative_groups.h>

#define BB 128
#define CC 64
#define TT 16384
#define RED 16
#define ROWS (BB * CC)          // 8192
#define T4 (TT / 4)             // 4096 float4 per row
#define NBLK 512                // coop grid: 2 blocks/CU guaranteed co-resident
#define NTHR 512                // 8 waves
#define ROUNDS (ROWS / NBLK)    // 16
#define F4PT (T4 / NTHR)        // 8 float4 per thread = row in registers

// fallback pipeline params (R5, proven 265us)
#define GB 16
#define NG (BB / GB)
#define ROWS_G (GB * CC)

typedef float f4 __attribute__((ext_vector_type(4)));

__device__ __forceinline__ float uload(const float* p) {
    return __hip_atomic_load(p, __ATOMIC_RELAXED, __HIP_MEMORY_SCOPE_AGENT);
}

// ============ single-pass persistent kernel: x through CUs ONCE ============
__global__ __launch_bounds__(NTHR, 2) void se_onepass(
        const f4* __restrict__ x,
        const float* __restrict__ w1, const float* __restrict__ b1,
        const float* __restrict__ w2, const float* __restrict__ b2,
        f4* __restrict__ out, float* __restrict__ s_out,
        float* __restrict__ u, int* __restrict__ cnt) {
    const int i = blockIdx.x;
    const int tid = threadIdx.x;
    const int lane = tid & 63, wid = tid >> 6;
    __shared__ float wsum[NTHR / 64];
    __shared__ float s_sh;

    for (int j = 0; j < ROUNDS; ++j) {
        const int row = j * NBLK + i;
        const int batch = row >> 6;
        const int chan  = row & (CC - 1);
        const f4* xr = x + (size_t)row * T4;

        // ---- stage the whole row in registers, accumulate sum ----
        f4 r[F4PT];
#pragma unroll
        for (int k = 0; k < F4PT; ++k) r[k] = xr[k * NTHR + tid];
        float sum = 0.f;
#pragma unroll
        for (int k = 0; k < F4PT; ++k) sum += (r[k].x + r[k].y) + (r[k].z + r[k].w);
#pragma unroll
        for (int off = 32; off; off >>= 1) sum += __shfl_down(sum, off, 64);
        if (lane == 0) wsum[wid] = sum;
        __syncthreads();                                    // sync1: wsum ready

        if (tid == 0) {
            float tot = 0.f;
#pragma unroll
            for (int w = 0; w < NTHR / 64; ++w) tot += wsum[w];
            u[row] = tot * (1.0f / TT);
            __threadfence();                                // publish u[row]
            atomicAdd(&cnt[batch], 1);                      // device-scope arrive
        }

        // ---- wave 0: wait for the batch's 64 rows, then MLP ----
        if (wid == 0) {
            while (__hip_atomic_load(&cnt[batch], __ATOMIC_ACQUIRE,
                                     __HIP_MEMORY_SCOPE_AGENT) < CC)
                __builtin_amdgcn_s_sleep(1);
            const int rr = lane & 15, q = lane >> 4;        // lane = q*16 + rr
            const float* ub  = u  + batch * CC + q * 16;
            const float* w1p = w1 + rr * CC + q * 16;
            float p = 0.f;
#pragma unroll
            for (int m = 0; m < 16; ++m) p = fmaf(uload(ub + m), w1p[m], p);
            p += __shfl_xor(p, 16, 64);
            p += __shfl_xor(p, 32, 64);                     // all lanes: h[rr] pre-bias
            const float h = fmaxf(p + b1[rr], 0.f);
            float prod = h * w2[chan * RED + rr];
            prod += __shfl_xor(prod, 1, 64);
            prod += __shfl_xor(prod, 2, 64);
            prod += __shfl_xor(prod, 4, 64);
            prod += __shfl_xor(prod, 8, 64);
            if (lane == 0) {
                const float sv = 1.0f / (1.0f + expf(-(prod + b2[chan])));
                s_sh = sv;
                s_out[row] = sv;
            }
        }
        __syncthreads();                                    // sync2: s_sh ready
        const float sv = s_sh;

        // ---- scale from registers, store (row never re-read) ----
        f4* orw = out + (size_t)row * T4;
#pragma unroll
        for (int k = 0; k < F4PT; ++k) {
            f4 v = r[k];
            v.x *= sv; v.y *= sv; v.z *= sv; v.w *= sv;
            orw[k * NTHR + tid] = v;
        }
        // next round's wsum writes happen after this point for every wave that
        // passed sync2; thread0 consumed wsum between sync1 and sync2 -> safe.
    }
}

// ==================== fallback: R5's 9-launch pipeline ====================
__device__ __forceinline__ float wave_mlp(const float* __restrict__ u,
                                          const float* __restrict__ w1,
                                          const float* __restrict__ b1,
                                          const float* __restrict__ w2,
                                          const float* __restrict__ b2,
                                          int b, int c, int lane) {
    const int r = lane & 15, q = lane >> 4;
    const float* ub  = u  + b * CC + q * 16;
    const float* w1p = w1 + r * CC + q * 16;
    float p = 0.f;
#pragma unroll
    for (int m = 0; m < 16; ++m) p = fmaf(ub[m], w1p[m], p);
    p += __shfl_xor(p, 16, 64);
    p += __shfl_xor(p, 32, 64);
    const float h = fmaxf(p + b1[r], 0.f);
    float prod = h * w2[c * RED + r];
    prod += __shfl_xor(prod, 1, 64);
    prod += __shfl_xor(prod, 2, 64);
    prod += __shfl_xor(prod, 4, 64);
    prod += __shfl_xor(prod, 8, 64);
    return 1.0f / (1.0f + expf(-(prod + b2[c])));
}

__global__ __launch_bounds__(256) void se_reduce0(const f4* __restrict__ x,
                                                  float* __restrict__ u) {
    const int row = blockIdx.x;
    const int tid = threadIdx.x;
    const int lane = tid & 63, wid = tid >> 6;
    const f4* xr = x + (size_t)row * T4;
    float sum = 0.f;
#pragma unroll 8
    for (int k = 0; k < T4 / 256; ++k) {
        f4 a = xr[tid + k * 256];
        sum += (a.x + a.y) + (a.z + a.w);
    }
#pragma unroll
    for (int off = 32; off; off >>= 1) sum += __shfl_down(sum, off, 64);
    __shared__ float wsum[4];
    if (lane == 0) wsum[wid] = sum;
    __syncthreads();
    if (tid == 0) u[row] = (wsum[0] + wsum[1] + wsum[2] + wsum[3]) * (1.0f / TT);
}

__global__ __launch_bounds__(256) void se_phase(
        const f4* __restrict__ x,
        const float* __restrict__ w1, const float* __restrict__ b1,
        const float* __restrict__ w2, const float* __restrict__ b2,
        f4* __restrict__ out, float* __restrict__ s_out,
        float* __restrict__ u, int g) {
    const int row = g * ROWS_G + blockIdx.x;
    const int tid = threadIdx.x;
    const int lane = tid & 63, wid = tid >> 6;
    __shared__ float wsum[4];
    __shared__ float s_sh;

    if (wid == 0) {
        const float sv = wave_mlp(u, w1, b1, w2, b2, row >> 6, row & (CC - 1), lane);
        if (lane == 0) { s_sh = sv; s_out[row] = sv; }
    }
    if (g + 1 < NG) {
        const f4* xn = x + (size_t)(row + ROWS_G) * T4;
        float sum = 0.f;
#pragma unroll 8
        for (int k = 0; k < T4 / 256; ++k) {
            f4 a = xn[tid + k * 256];
            sum += (a.x + a.y) + (a.z + a.w);
        }
#pragma unroll
        for (int off = 32; off; off >>= 1) sum += __shfl_down(sum, off, 64);
        if (lane == 0) wsum[wid] = sum;
    }
    __syncthreads();
    if (g + 1 < NG && tid == 0)
        u[row + ROWS_G] = (wsum[0] + wsum[1] + wsum[2] + wsum[3]) * (1.0f / TT);

    const float sv = s_sh;
    const f4* xr = x + (size_t)row * T4;
    f4* orw = out + (size_t)row * T4;
#pragma unroll 8
    for (int k = 0; k < T4 / 256; ++k) {
        f4 v = xr[tid + k * 256];
        v.x *= sv; v.y *= sv; v.z *= sv; v.w *= sv;
        __builtin_nontemporal_store(v, &orw[tid + k * 256]);
    }
}

extern "C" void kernel_launch(void* const* d_in, const int* in_sizes, int n_in,
                              void* d_out, int out_size, void* d_ws, size_t ws_size,
                              hipStream_t stream) {
    const f4*    x  = (const f4*)d_in[0];
    const float* w1 = (const float*)d_in[1];
    const float* b1 = (const float*)d_in[2];
    const float* w2 = (const float*)d_in[3];
    const float* b2 = (const float*)d_in[4];

    f4*    out   = (f4*)d_out;                   // [B*C*T] x_recal, then [B*C] s
    float* s_out = (float*)d_out + (size_t)ROWS * TT;
    float* u_ws  = (float*)d_ws;                 // [B*C] means
    int*   cnt   = (int*)(u_ws + ROWS);          // [B] batch arrival counters

    hipMemsetAsync(cnt, 0, BB * sizeof(int), stream);  // deterministic per call

    void* args[] = {(void*)&x, (void*)&w1, (void*)&b1, (void*)&w2, (void*)&b2,
                    (void*)&out, (void*)&s_out, (void*)&u_ws, (void*)&cnt};
    hipError_t err = hipLaunchCooperativeKernel((const void*)se_onepass,
                                                dim3(NBLK), dim3(NTHR),
                                                args, 0, stream);
    if (err != hipSuccess) {
        // proven fallback: grouped L3 pipeline (R5)
        se_reduce0<<<ROWS_G, 256, 0, stream>>>(x, u_ws);
        for (int g = 0; g < NG; ++g)
            se_phase<<<ROWS_G, 256, 0, stream>>>(x, w1, b1, w2, b2,
                                                 out, s_out, u_ws, g);
    }
}

// Round 9
// 285.264 us; speedup vs baseline: 3.4705x; 3.4705x over previous
//
#include <hip/hip_runtime.h>

#define BB 128
#define CC 64
#define TT 16384
#define RED 16
#define ROWS (BB * CC)          // 8192
#define T4 (TT / 4)             // 4096 float4 per row
#define GB 16                   // batches per L3-resident group (64 MiB of x)
#define NG (BB / GB)            // 8 groups
#define ROWS_G (GB * CC)        // 1024 rows per group == grid per launch

typedef float f4 __attribute__((ext_vector_type(4)));

// One full wave computes s[b][c]; returns sv on ALL lanes.
__device__ __forceinline__ float wave_mlp(const float* __restrict__ u,
                                          const float* __restrict__ w1,
                                          const float* __restrict__ b1,
                                          const float* __restrict__ w2,
                                          const float* __restrict__ b2,
                                          int b, int c, int lane) {
    const int r = lane & 15, q = lane >> 4;      // lane = q*16 + r
    const float* ub  = u  + b * CC + q * 16;
    const float* w1p = w1 + r * CC + q * 16;
    float p = 0.f;
#pragma unroll
    for (int m = 0; m < 16; ++m) p = fmaf(ub[m], w1p[m], p);
    p += __shfl_xor(p, 16, 64);                  // sum 4 q-partials
    p += __shfl_xor(p, 32, 64);                  // -> every lane holds h[r]
    const float h = fmaxf(p + b1[r], 0.f);
    float prod = h * w2[c * RED + r];
    prod += __shfl_xor(prod, 1, 64);             // sum the 16 r's
    prod += __shfl_xor(prod, 2, 64);
    prod += __shfl_xor(prod, 4, 64);
    prod += __shfl_xor(prod, 8, 64);
    return 1.0f / (1.0f + expf(-(prod + b2[c])));
}

// ---------------- kernel 1: mean of group-0 rows (HBM read, nt) ----------------
__global__ __launch_bounds__(256) void se_reduce0(const f4* __restrict__ x,
                                                  float* __restrict__ u) {
    const int row = blockIdx.x;
    const int tid = threadIdx.x;
    const int lane = tid & 63, wid = tid >> 6;
    const f4* xr = x + (size_t)row * T4;
    float sum = 0.f;
#pragma unroll 8
    for (int k = 0; k < T4 / 256; ++k) {
        f4 a = __builtin_nontemporal_load(&xr[tid + k * 256]);
        sum += (a.x + a.y) + (a.z + a.w);
    }
#pragma unroll
    for (int off = 32; off; off >>= 1) sum += __shfl_down(sum, off, 64);
    __shared__ float wsum[4];
    if (lane == 0) wsum[wid] = sum;
    __syncthreads();
    if (tid == 0) u[row] = (wsum[0] + wsum[1] + wsum[2] + wsum[3]) * (1.0f / TT);
}

// ---- kernel 2 (x8): {reduce group g+1 from HBM} + {MLP + scale group g from L3} ----
// All x traffic nontemporal: reduce-leg lines are next served from L3 (L2 alloc
// is pure thrash: 512 MiB stream through 32 MiB L2); scale-leg lines are dead
// after use; stores must not evict the L3-resident x slices.
__global__ __launch_bounds__(256) void se_phase(
        const f4* __restrict__ x,
        const float* __restrict__ w1, const float* __restrict__ b1,
        const float* __restrict__ w2, const float* __restrict__ b2,
        f4* __restrict__ out, float* __restrict__ s_out,
        float* __restrict__ u, int g) {
    const int row = g * ROWS_G + blockIdx.x;
    const int tid = threadIdx.x;
    const int lane = tid & 63, wid = tid >> 6;
    __shared__ float wsum[4];
    __shared__ float s_sh;

    // wave 0: excitation MLP for this row (u is cache-hot from previous launch)
    if (wid == 0) {
        const float sv = wave_mlp(u, w1, b1, w2, b2, row >> 6, row & (CC - 1), lane);
        if (lane == 0) { s_sh = sv; s_out[row] = sv; }
    }

    // all waves: reduce row+ROWS_G (group g+1) — pure HBM read stream
    if (g + 1 < NG) {
        const f4* xn = x + (size_t)(row + ROWS_G) * T4;
        float sum = 0.f;
#pragma unroll 8
        for (int k = 0; k < T4 / 256; ++k) {
            f4 a = __builtin_nontemporal_load(&xn[tid + k * 256]);
            sum += (a.x + a.y) + (a.z + a.w);
        }
#pragma unroll
        for (int off = 32; off; off >>= 1) sum += __shfl_down(sum, off, 64);
        if (lane == 0) wsum[wid] = sum;
    }
    __syncthreads();                             // s_sh + wsum ready
    if (g + 1 < NG && tid == 0)
        u[row + ROWS_G] = (wsum[0] + wsum[1] + wsum[2] + wsum[3]) * (1.0f / TT);

    // all waves: scale group-g row — reads served by L3, nt stores
    const float sv = s_sh;
    const f4* xr = x + (size_t)row * T4;
    f4* orw = out + (size_t)row * T4;
#pragma unroll 8
    for (int k = 0; k < T4 / 256; ++k) {
        f4 v = __builtin_nontemporal_load(&xr[tid + k * 256]);
        v.x *= sv; v.y *= sv; v.z *= sv; v.w *= sv;
        __builtin_nontemporal_store(v, &orw[tid + k * 256]);
    }
}

extern "C" void kernel_launch(void* const* d_in, const int* in_sizes, int n_in,
                              void* d_out, int out_size, void* d_ws, size_t ws_size,
                              hipStream_t stream) {
    const f4*    x  = (const f4*)d_in[0];
    const float* w1 = (const float*)d_in[1];
    const float* b1 = (const float*)d_in[2];
    const float* w2 = (const float*)d_in[3];
    const float* b2 = (const float*)d_in[4];

    f4*    out   = (f4*)d_out;                   // [B*C*T] x_recal, then [B*C] s
    float* s_out = (float*)d_out + (size_t)ROWS * TT;
    float* u_ws  = (float*)d_ws;                 // [B*C] means

    se_reduce0<<<ROWS_G, 256, 0, stream>>>(x, u_ws);
    for (int g = 0; g < NG; ++g)
        se_phase<<<ROWS_G, 256, 0, stream>>>(x, w1, b1, w2, b2,
                                             out, s_out, u_ws, g);
}

// Round 10
// 265.998 us; speedup vs baseline: 3.7218x; 1.0724x over previous
//
#include <hip/hip_runtime.h>

#define BB 128
#define CC 64
#define TT 16384
#define RED 16
#define ROWS (BB * CC)          // 8192
#define T4 (TT / 4)             // 4096 float4 per row
#define GB 16                   // batches per L3-resident group (64 MiB of x)
#define NG (BB / GB)            // 8 groups
#define ROWS_G (GB * CC)        // 1024 rows per group == grid per launch

typedef float f4 __attribute__((ext_vector_type(4)));

// One full wave computes s[b][c]; returns sv on ALL lanes.
__device__ __forceinline__ float wave_mlp(const float* __restrict__ u,
                                          const float* __restrict__ w1,
                                          const float* __restrict__ b1,
                                          const float* __restrict__ w2,
                                          const float* __restrict__ b2,
                                          int b, int c, int lane) {
    const int r = lane & 15, q = lane >> 4;      // lane = q*16 + r
    const float* ub  = u  + b * CC + q * 16;
    const float* w1p = w1 + r * CC + q * 16;
    float p = 0.f;
#pragma unroll
    for (int j = 0; j < 16; ++j) p = fmaf(ub[j], w1p[j], p);
    p += __shfl_xor(p, 16, 64);                  // sum 4 q-partials
    p += __shfl_xor(p, 32, 64);                  // -> every lane holds h[r]
    const float h = fmaxf(p + b1[r], 0.f);
    float prod = h * w2[c * RED + r];
    prod += __shfl_xor(prod, 1, 64);             // sum the 16 r's
    prod += __shfl_xor(prod, 2, 64);
    prod += __shfl_xor(prod, 4, 64);
    prod += __shfl_xor(prod, 8, 64);
    return 1.0f / (1.0f + expf(-(prod + b2[c])));
}

// ---------------- kernel 1: mean of group-0 rows (HBM read) ----------------
__global__ __launch_bounds__(256) void se_reduce0(const f4* __restrict__ x,
                                                  float* __restrict__ u) {
    const int row = blockIdx.x;
    const int tid = threadIdx.x;
    const int lane = tid & 63, wid = tid >> 6;
    const f4* xr = x + (size_t)row * T4;
    float s0 = 0.f, s1 = 0.f;
#pragma unroll 8
    for (int k = 0; k < T4 / 256; k += 2) {
        f4 a = xr[tid + k * 256];
        f4 b = xr[tid + (k + 1) * 256];
        s0 += (a.x + a.y) + (a.z + a.w);
        s1 += (b.x + b.y) + (b.z + b.w);
    }
    float sum = s0 + s1;
#pragma unroll
    for (int off = 32; off; off >>= 1) sum += __shfl_down(sum, off, 64);
    __shared__ float wsum[4];
    if (lane == 0) wsum[wid] = sum;
    __syncthreads();
    if (tid == 0) u[row] = (wsum[0] + wsum[1] + wsum[2] + wsum[3]) * (1.0f / TT);
}

// ---- kernel 2 (x8): {reduce group g+1 from HBM} + {MLP + scale group g from L3} ----
// Cache policy (measured matrix R5/R6/R8): reduce-leg loads NORMAL (must
// allocate in L3 so next phase's scale-leg hits), stores NT (must not evict
// the L3-resident x slices). nt on loads or normal on stores both regress.
__global__ __launch_bounds__(256) void se_phase(
        const f4* __restrict__ x,
        const float* __restrict__ w1, const float* __restrict__ b1,
        const float* __restrict__ w2, const float* __restrict__ b2,
        f4* __restrict__ out, float* __restrict__ s_out,
        float* __restrict__ u, int g) {
    const int row = g * ROWS_G + blockIdx.x;
    const int tid = threadIdx.x;
    const int lane = tid & 63, wid = tid >> 6;
    __shared__ float wsum[4];
    __shared__ float s_sh;

    // wave 0: excitation MLP for this row (u is cache-hot from previous launch)
    if (wid == 0) {
        const float sv = wave_mlp(u, w1, b1, w2, b2, row >> 6, row & (CC - 1), lane);
        if (lane == 0) { s_sh = sv; s_out[row] = sv; }
    }

    // all waves: reduce row+ROWS_G (group g+1) — pure HBM read stream
    if (g + 1 < NG) {
        const f4* xn = x + (size_t)(row + ROWS_G) * T4;
        float s0 = 0.f, s1 = 0.f;
#pragma unroll 8
        for (int k = 0; k < T4 / 256; k += 2) {
            f4 a = xn[tid + k * 256];
            f4 b = xn[tid + (k + 1) * 256];
            s0 += (a.x + a.y) + (a.z + a.w);
            s1 += (b.x + b.y) + (b.z + b.w);
        }
        float sum = s0 + s1;
#pragma unroll
        for (int off = 32; off; off >>= 1) sum += __shfl_down(sum, off, 64);
        if (lane == 0) wsum[wid] = sum;
    }
    __syncthreads();                             // s_sh + wsum ready
    if (g + 1 < NG && tid == 0)
        u[row + ROWS_G] = (wsum[0] + wsum[1] + wsum[2] + wsum[3]) * (1.0f / TT);

    // all waves: scale group-g row — reads served by L3, nt-stores to HBM
    const float sv = s_sh;
    const f4* xr = x + (size_t)row * T4;
    f4* orw = out + (size_t)row * T4;
#pragma unroll 8
    for (int k = 0; k < T4 / 256; ++k) {
        f4 v = xr[tid + k * 256];
        v.x *= sv; v.y *= sv; v.z *= sv; v.w *= sv;
        __builtin_nontemporal_store(v, &orw[tid + k * 256]);
    }
}

extern "C" void kernel_launch(void* const* d_in, const int* in_sizes, int n_in,
                              void* d_out, int out_size, void* d_ws, size_t ws_size,
                              hipStream_t stream) {
    const f4*    x  = (const f4*)d_in[0];
    const float* w1 = (const float*)d_in[1];
    const float* b1 = (const float*)d_in[2];
    const float* w2 = (const float*)d_in[3];
    const float* b2 = (const float*)d_in[4];

    f4*    out   = (f4*)d_out;                   // [B*C*T] x_recal, then [B*C] s
    float* s_out = (float*)d_out + (size_t)ROWS * TT;
    float* u_ws  = (float*)d_ws;                 // [B*C] means

    se_reduce0<<<ROWS_G, 256, 0, stream>>>(x, u_ws);
    for (int g = 0; g < NG; ++g)
        se_phase<<<ROWS_G, 256, 0, stream>>>(x, w1, b1, w2, b2,
                                             out, s_out, u_ws, g);
}